// Round 4
// baseline (866.688 us; speedup 1.0000x reference)
//
#include <hip/hip_runtime.h>
#include <hip/hip_bf16.h>
#include <cstdint>
#include <cstddef>

typedef __attribute__((ext_vector_type(4))) float f32x4;
typedef __attribute__((ext_vector_type(8))) short s16x8;

#define D_ 128
#define H_ 512
#define CAT_ 384
#define BM 64
#define PH 520                      // shared LDS buffer pitch (bf16 elems): 512+8
#define PYF 132                     // y pitch (f32)
#define LDS_BYTES (BM * PH * 2)     // 66560 -> 2 blocks/CU

__device__ __forceinline__ unsigned short f2bf(float x) {
  union { float f; unsigned u; } t; t.f = x;
  return (unsigned short)((t.u + 0x8000u) >> 16);  // round-half-up (abs err < 2^-8 rel)
}

__global__ __launch_bounds__(512, 4)
void edge_mlp_fused(const float* __restrict__ efeat,
                    const float* __restrict__ src_feat,
                    const float* __restrict__ dst_feat,
                    const int* __restrict__ src_idx,
                    const int* __restrict__ dst_idx,
                    const unsigned short* __restrict__ W1T,
                    const unsigned short* __restrict__ W2T,
                    const unsigned short* __restrict__ W3T,
                    const float* __restrict__ b1,
                    const float* __restrict__ b2,
                    const float* __restrict__ b3,
                    const float* __restrict__ gamma,
                    const float* __restrict__ beta,
                    float* __restrict__ out) {
  extern __shared__ char smem[];
  unsigned short* buf = (unsigned short*)smem;   // cat -> h1 -> h2 (barrier-separated reuse)
  float* yb = (float*)smem;                      // y (f32) overlays same region after GEMM3

  const int tid = threadIdx.x;
  const int lane = tid & 63;
  const int wave = tid >> 6;                     // 0..7
  const size_t e0 = (size_t)blockIdx.x * BM;

  const int arow = lane & 15;
  const int ak8 = (lane >> 4) * 8;
  const int c0 = arow, r0 = (lane >> 4) * 4;

  // ================= phase 0: gather + concat -> bf16 LDS =================
  {
    // efeat: 64 contiguous rows = 32 KB, perfectly coalesced f32x4 loads
    const f32x4* epan = (const f32x4*)(efeat + e0 * D_);
    #pragma unroll
    for (int k = 0; k < 4; ++k) {
      const int idx = tid + 512 * k;             // f32x4 index into 64x128 panel
      const f32x4 v = epan[idx];
      const int row = idx >> 5, col = (idx & 31) * 4;
      ushort4 w;
      w.x = f2bf(v[0]); w.y = f2bf(v[1]); w.z = f2bf(v[2]); w.w = f2bf(v[3]);
      *(ushort4*)(buf + row * PH + col) = w;
    }
    // src/dst gathers: 8 threads per row; per step the 8 lanes cover one 128B line
    const int row = tid >> 3, q = tid & 7;
    const float* ps = src_feat + (size_t)src_idx[e0 + row] * D_;
    const float* pd = dst_feat + (size_t)dst_idx[e0 + row] * D_;
    unsigned short* crow = buf + row * PH;
    #pragma unroll
    for (int i = 0; i < 4; ++i) {
      const int c = i * 32 + q * 4;
      const f32x4 v = *(const f32x4*)(ps + c);
      const f32x4 u = *(const f32x4*)(pd + c);
      ushort4 w;
      w.x = f2bf(v[0]); w.y = f2bf(v[1]); w.z = f2bf(v[2]); w.w = f2bf(v[3]);
      *(ushort4*)(crow + D_ + c) = w;
      w.x = f2bf(u[0]); w.y = f2bf(u[1]); w.z = f2bf(u[2]); w.w = f2bf(u[3]);
      *(ushort4*)(crow + 2 * D_ + c) = w;
    }
  }
  __syncthreads();

  // ================= GEMM1: cat[64x384] @ W1 -> silu -> h1 (same buffer) =================
  {
    f32x4 acc[4][4];
    #pragma unroll
    for (int m = 0; m < 4; ++m)
      #pragma unroll
      for (int n = 0; n < 4; ++n) acc[m][n] = (f32x4){0.f, 0.f, 0.f, 0.f};

    const unsigned short* bp[4];
    #pragma unroll
    for (int n = 0; n < 4; ++n)
      bp[n] = W1T + (size_t)(wave * 64 + n * 16 + arow) * CAT_ + ak8;
    const unsigned short* ap = buf + arow * PH + ak8;

    #pragma unroll 2
    for (int kk = 0; kk < 12; ++kk) {
      s16x8 b[4], a[4];
      #pragma unroll
      for (int n = 0; n < 4; ++n) b[n] = *(const s16x8*)(bp[n] + kk * 32);
      #pragma unroll
      for (int m = 0; m < 4; ++m) a[m] = *(const s16x8*)(ap + m * 16 * PH + kk * 32);
      #pragma unroll
      for (int m = 0; m < 4; ++m)
        #pragma unroll
        for (int n = 0; n < 4; ++n)
          acc[m][n] = __builtin_amdgcn_mfma_f32_16x16x32_bf16(a[m], b[n], acc[m][n], 0, 0, 0);
    }
    __syncthreads();   // all waves done READING cat before h1 overwrites it

    #pragma unroll
    for (int n = 0; n < 4; ++n) {
      const int col = wave * 64 + n * 16 + c0;
      const float bb = b1[col];
      #pragma unroll
      for (int m = 0; m < 4; ++m)
        #pragma unroll
        for (int r = 0; r < 4; ++r) {
          const float x = acc[m][n][r] + bb;
          buf[(m * 16 + r0 + r) * PH + col] = f2bf(x / (1.0f + __expf(-x)));
        }
    }
  }
  __syncthreads();

  // ================= GEMM2: h1[64x512] @ W2 -> silu -> h2 (same buffer) =================
  {
    f32x4 acc[4][4];
    #pragma unroll
    for (int m = 0; m < 4; ++m)
      #pragma unroll
      for (int n = 0; n < 4; ++n) acc[m][n] = (f32x4){0.f, 0.f, 0.f, 0.f};

    const unsigned short* bp[4];
    #pragma unroll
    for (int n = 0; n < 4; ++n)
      bp[n] = W2T + (size_t)(wave * 64 + n * 16 + arow) * H_ + ak8;
    const unsigned short* ap = buf + arow * PH + ak8;

    #pragma unroll 2
    for (int kk = 0; kk < 16; ++kk) {
      s16x8 b[4], a[4];
      #pragma unroll
      for (int n = 0; n < 4; ++n) b[n] = *(const s16x8*)(bp[n] + kk * 32);
      #pragma unroll
      for (int m = 0; m < 4; ++m) a[m] = *(const s16x8*)(ap + m * 16 * PH + kk * 32);
      #pragma unroll
      for (int m = 0; m < 4; ++m)
        #pragma unroll
        for (int n = 0; n < 4; ++n)
          acc[m][n] = __builtin_amdgcn_mfma_f32_16x16x32_bf16(a[m], b[n], acc[m][n], 0, 0, 0);
    }
    __syncthreads();   // all waves done READING h1

    #pragma unroll
    for (int n = 0; n < 4; ++n) {
      const int col = wave * 64 + n * 16 + c0;
      const float bb = b2[col];
      #pragma unroll
      for (int m = 0; m < 4; ++m)
        #pragma unroll
        for (int r = 0; r < 4; ++r) {
          const float x = acc[m][n][r] + bb;
          buf[(m * 16 + r0 + r) * PH + col] = f2bf(x / (1.0f + __expf(-x)));
        }
    }
  }
  __syncthreads();

  // ================= GEMM3: h2[64x512] @ W3 + b3 -> y (f32, same buffer) =================
  {
    f32x4 acc[4];
    #pragma unroll
    for (int m = 0; m < 4; ++m) acc[m] = (f32x4){0.f, 0.f, 0.f, 0.f};

    const unsigned short* bp = W3T + (size_t)(wave * 16 + arow) * H_ + ak8;
    const unsigned short* ap = buf + arow * PH + ak8;

    #pragma unroll 4
    for (int kk = 0; kk < 16; ++kk) {
      s16x8 b = *(const s16x8*)(bp + kk * 32);
      s16x8 a[4];
      #pragma unroll
      for (int m = 0; m < 4; ++m) a[m] = *(const s16x8*)(ap + m * 16 * PH + kk * 32);
      #pragma unroll
      for (int m = 0; m < 4; ++m)
        acc[m] = __builtin_amdgcn_mfma_f32_16x16x32_bf16(a[m], b, acc[m], 0, 0, 0);
    }
    __syncthreads();   // all waves done READING h2 before y overlays the buffer

    const int col = wave * 16 + c0;
    const float bb = b3[col];
    #pragma unroll
    for (int m = 0; m < 4; ++m)
      #pragma unroll
      for (int r = 0; r < 4; ++r)
        yb[(m * 16 + r0 + r) * PYF + col] = acc[m][r] + bb;
  }
  __syncthreads();

  // ================= LayerNorm (f32) + store: 8 threads per row =================
  {
    const int row = tid >> 3, j = tid & 7;
    const float* yr = yb + row * PYF + j * 16;
    f32x4 v[4];
    float sum = 0.f, ss = 0.f;
    #pragma unroll
    for (int q = 0; q < 4; ++q) {
      v[q] = *(const f32x4*)(yr + q * 4);
      #pragma unroll
      for (int r = 0; r < 4; ++r) { sum += v[q][r]; ss += v[q][r] * v[q][r]; }
    }
    sum += __shfl_xor(sum, 1, 64); ss += __shfl_xor(ss, 1, 64);
    sum += __shfl_xor(sum, 2, 64); ss += __shfl_xor(ss, 2, 64);
    sum += __shfl_xor(sum, 4, 64); ss += __shfl_xor(ss, 4, 64);
    const float mu = sum * (1.0f / 128.0f);
    const float var = ss * (1.0f / 128.0f) - mu * mu;
    const float rstd = rsqrtf(var + 1e-5f);
    float* orow = out + (e0 + row) * D_ + j * 16;
    #pragma unroll
    for (int q = 0; q < 4; ++q) {
      const f32x4 g = *(const f32x4*)(gamma + j * 16 + q * 4);
      const f32x4 bt = *(const f32x4*)(beta + j * 16 + q * 4);
      f32x4 o;
      #pragma unroll
      for (int r = 0; r < 4; ++r)
        o[r] = (v[q][r] - mu) * rstd * g[r] + bt[r];
      *(f32x4*)(orow + q * 4) = o;
    }
  }
}

// W [K][N] f32 -> Wt [N][K] bf16 (tiled transpose, coalesced both sides)
__global__ void prep_wt(const float* __restrict__ src, unsigned short* __restrict__ dst,
                        int K, int N) {
  __shared__ float tile[32][33];
  const int bk = blockIdx.x * 32, bn = blockIdx.y * 32;
  const int tx = threadIdx.x & 31, ty = threadIdx.x >> 5;
  #pragma unroll
  for (int i = ty; i < 32; i += 8)
    tile[i][tx] = src[(size_t)(bk + i) * N + bn + tx];
  __syncthreads();
  #pragma unroll
  for (int i = ty; i < 32; i += 8)
    dst[(size_t)(bn + i) * K + bk + tx] = f2bf(tile[tx][i]);
}

extern "C" void kernel_launch(void* const* d_in, const int* in_sizes, int n_in,
                              void* d_out, int out_size, void* d_ws, size_t ws_size,
                              hipStream_t stream) {
  const float* efeat    = (const float*)d_in[0];
  const float* src_feat = (const float*)d_in[1];
  const float* dst_feat = (const float*)d_in[2];
  const int*   src_idx  = (const int*)d_in[3];
  const int*   dst_idx  = (const int*)d_in[4];
  const float* W1 = (const float*)d_in[5];
  const float* b1 = (const float*)d_in[6];
  const float* W2 = (const float*)d_in[7];
  const float* b2 = (const float*)d_in[8];
  const float* W3 = (const float*)d_in[9];
  const float* b3 = (const float*)d_in[10];
  const float* gamma = (const float*)d_in[11];
  const float* beta  = (const float*)d_in[12];

  unsigned short* W1T = (unsigned short*)d_ws;          // [512][384]
  unsigned short* W2T = W1T + 512 * 384;                // [512][512]
  unsigned short* W3T = W2T + 512 * 512;                // [128][512]

  (void)hipFuncSetAttribute((const void*)edge_mlp_fused,
                            hipFuncAttributeMaxDynamicSharedMemorySize, LDS_BYTES);

  prep_wt<<<dim3(12, 16), 256, 0, stream>>>(W1, W1T, CAT_, H_);
  prep_wt<<<dim3(16, 16), 256, 0, stream>>>(W2, W2T, H_, H_);
  prep_wt<<<dim3(16, 4),  256, 0, stream>>>(W3, W3T, H_, D_);

  const int nblocks = 400000 / BM; // 6250, exact
  edge_mlp_fused<<<nblocks, 512, LDS_BYTES, stream>>>(
      efeat, src_feat, dst_feat, src_idx, dst_idx,
      W1T, W2T, W3T, b1, b2, b3, gamma, beta, (float*)d_out);
}